// Round 19
// baseline (180.714 us; speedup 1.0000x reference)
//
#include <hip/hip_runtime.h>
#include <hip/hip_fp16.h>
#include <hip/hip_fp8.h>
#include <math.h>

#define NEG_SLOPE 0.2f

typedef short short8v __attribute__((ext_vector_type(8)));
typedef _Float16 half8v __attribute__((ext_vector_type(8)));
typedef float f32x4 __attribute__((ext_vector_type(4)));
typedef float f32x2 __attribute__((ext_vector_type(2)));

__device__ __forceinline__ unsigned short f2bf(float f) {
    unsigned int u = __builtin_bit_cast(unsigned int, f);
    u += 0x7FFFu + ((u >> 16) & 1u);   // RNE
    return (unsigned short)(u >> 16);
}

__device__ __forceinline__ unsigned char f2fp8(float f) {
    __hip_fp8_e4m3 q(f);
    return (unsigned char)q.__x;
}

__device__ __forceinline__ float fp82f(unsigned char b) {
    __hip_fp8_e4m3 q;
    q.__x = (__hip_fp8_storage_t)b;
    return (float)q;
}

// hardware packed fp8->f32 decode (OCP e4m3 on gfx950); 2 instrs per 4 bytes
__device__ __forceinline__ void fma_fp8x4(float4& acc, float w, unsigned v) {
#if __has_builtin(__builtin_amdgcn_cvt_pk_f32_fp8)
    f32x2 lo2 = __builtin_amdgcn_cvt_pk_f32_fp8(v, false);   // bytes 0,1
    f32x2 hi2 = __builtin_amdgcn_cvt_pk_f32_fp8(v, true);    // bytes 2,3
    acc.x += w * lo2[0];
    acc.y += w * lo2[1];
    acc.z += w * hi2[0];
    acc.w += w * hi2[1];
#else
    acc.x += w * fp82f((unsigned char)(v & 0xffu));
    acc.y += w * fp82f((unsigned char)((v >> 8) & 0xffu));
    acc.z += w * fp82f((unsigned char)((v >> 16) & 0xffu));
    acc.w += w * fp82f((unsigned char)(v >> 24));
#endif
}

// ---------------- CSR build: degree count + weight converts (merged) ----------------
__global__ void k_deg_cvt(const int* __restrict__ ei, int E, int N, int degB,
                          int* __restrict__ deg, int* __restrict__ rank,
                          const float* __restrict__ W1, const float* __restrict__ W2,
                          unsigned short* __restrict__ w1t, __half* __restrict__ w2t) {
    int b = blockIdx.x;
    if (b < degB) {
        int i = b * 256 + threadIdx.x;
        int Et = E + N;
        if (i >= Et) return;
        int dst = (i < E) ? ei[E + i] : (i - E);
        rank[i] = atomicAdd(&deg[dst], 1);
    } else {
        int bb = b - degB;
        int k = threadIdx.x;
        if (bb < 256) {
            w1t[bb * 256 + k] = f2bf(W1[k * 256 + bb]);
        } else {
            int c = bb - 256;
            w2t[c * 256 + k] = __float2half((c < 40) ? W2[k * 40 + c] : 0.f);
        }
    }
}

__global__ void k_scan_block(const int* __restrict__ deg, int N, int* __restrict__ excl, int* __restrict__ bsums) {
    __shared__ int s[256];
    int b = blockIdx.x, t = threadIdx.x;
    int i = b * 256 + t;
    int v = (i < N) ? deg[i] : 0;
    s[t] = v;
    __syncthreads();
    for (int off = 1; off < 256; off <<= 1) {
        int add = (t >= off) ? s[t - off] : 0;
        __syncthreads();
        s[t] += add;
        __syncthreads();
    }
    int incl = s[t];
    if (i < N) excl[i] = incl - v;
    if (t == 255) bsums[b] = incl;
}

// fused: each block reduces bsums[0..b) (NB<=256) then adds to its row_start slice
__global__ void k_scan_add(int* __restrict__ row_start, const int* __restrict__ bsums,
                           int N, int Et, int NB) {
    __shared__ int ws[4];
    int b = blockIdx.x, t = threadIdx.x;
    int wv = t >> 6, l = t & 63;
    int v = (t < b && t < NB) ? bsums[t] : 0;
    for (int off = 32; off; off >>= 1) v += __shfl_xor(v, off);
    if (l == 0) ws[wv] = v;
    __syncthreads();
    int total = ws[0] + ws[1] + ws[2] + ws[3];
    int i = b * 256 + t;
    if (i < N) row_start[i] += total;
    if (i == 0) row_start[N] = Et;
}

__global__ void k_scatter(const int* __restrict__ ei, const int* __restrict__ rank, int E, int N,
                          const int* __restrict__ row_start, int* __restrict__ csr_src) {
    int i = blockIdx.x * blockDim.x + threadIdx.x;
    int Et = E + N;
    if (i >= Et) return;
    int src, dst;
    if (i < E) { src = ei[i]; dst = ei[E + i]; }
    else       { src = i - E; dst = i - E; }
    csr_src[row_start[dst] + rank[i]] = src;
}

// ---------------- GEMM1 MFMA: one head per block (grid x=row-tile, y=head) ----------------
// A fragments direct from global x (L3-served re-reads); 33KB Bs LDS; ONE barrier per block.
#define LDP 264
__global__ __launch_bounds__(256) void k_gemm1_mfma(const float* __restrict__ x,
                                                    const unsigned short* __restrict__ w1t,
                                                    const float* __restrict__ att_s,
                                                    const float* __restrict__ att_d,
                                                    unsigned char* __restrict__ h1f,
                                                    float* __restrict__ as1, float* __restrict__ ad1, int N) {
    __shared__ unsigned short Bs[64 * LDP];
    int tid = threadIdx.x;
    int row0 = blockIdx.x * 64;
    int head = blockIdx.y;
    int w = tid >> 6, l = tid & 63;
    int hi = l >> 4, lo = l & 15;
    // stage B for this head (coalesced), in parallel with A reg-loads below
#pragma unroll
    for (int it = 0; it < 8; it++) {
        int c = tid + it * 256;
        int r = c >> 5, q = c & 31;
        uint4 vb = ((const uint4*)w1t)[(size_t)(head * 64 + r) * 32 + q];
        *(uint4*)&Bs[r * LDP + q * 8] = vb;
    }
    // A fragments: lane owns row row0+16w+lo, features kk*32+8*hi..+7 — direct from x, cvt to bf16
    int arow = row0 + 16 * w + lo;
    bool rowok = arow < N;
    size_t xbase = (size_t)(rowok ? arow : 0) * 64;   // in float4 units
    short8v a[8];
#pragma unroll
    for (int kk = 0; kk < 8; kk++) {
        float4 f0 = make_float4(0, 0, 0, 0), f1 = f0;
        if (rowok) {
            f0 = ((const float4*)x)[xbase + kk * 8 + 2 * hi];
            f1 = ((const float4*)x)[xbase + kk * 8 + 2 * hi + 1];
        }
        short8v av;
        av[0] = (short)f2bf(f0.x); av[1] = (short)f2bf(f0.y);
        av[2] = (short)f2bf(f0.z); av[3] = (short)f2bf(f0.w);
        av[4] = (short)f2bf(f1.x); av[5] = (short)f2bf(f1.y);
        av[6] = (short)f2bf(f1.z); av[7] = (short)f2bf(f1.w);
        a[kk] = av;
    }
    __syncthreads();                   // Bs ready (the only barrier)
    f32x4 acc[4] = {};
#pragma unroll
    for (int kk = 0; kk < 8; kk++) {
#pragma unroll
        for (int jb = 0; jb < 4; jb++) {
            short8v b = *(const short8v*)&Bs[(16 * jb + lo) * LDP + kk * 32 + 8 * hi];
            acc[jb] = __builtin_amdgcn_mfma_f32_16x16x32_bf16(a[kk], b, acc[jb], 0, 0, 0);
        }
    }
    float asr[4], adr[4];
#pragma unroll
    for (int jb = 0; jb < 4; jb++) {
        int c = head * 64 + lo + 16 * jb;
        asr[jb] = att_s[c];
        adr[jb] = att_d[c];
    }
#pragma unroll
    for (int j = 0; j < 4; j++) {
        int rr = 16 * w + 4 * hi + j;
        int r = row0 + rr;
        float s = 0.f, d = 0.f;
#pragma unroll
        for (int jb = 0; jb < 4; jb++) {
            float v = acc[jb][j];
            s += v * asr[jb];
            d += v * adr[jb];
            if (r < N) h1f[(size_t)r * 256 + head * 64 + lo + 16 * jb] = f2fp8(v);
        }
        s += __shfl_xor(s, 1); s += __shfl_xor(s, 2); s += __shfl_xor(s, 4); s += __shfl_xor(s, 8);
        d += __shfl_xor(d, 1); d += __shfl_xor(d, 2); d += __shfl_xor(d, 4); d += __shfl_xor(d, 8);
        if (lo == 0 && r < N) {
            as1[r * 4 + head] = s;
            ad1[r * 4 + head] = d;
        }
    }
}

// ---------------- layer1 fused softmax-aggregation: 2-phase, 8-deep gather unroll, fp8 table ----------------
__global__ __launch_bounds__(256) void k_agg1(const unsigned char* __restrict__ h1f, const float* __restrict__ as1,
                                              const float* __restrict__ ad1, const int* __restrict__ row_start,
                                              const int* __restrict__ csr_src, const float* __restrict__ b1,
                                              __half* __restrict__ hbh, int N) {
    __shared__ int    s_src[4][64];
    __shared__ float4 s_w[4][64];
    int wv = threadIdx.x >> 6, l = threadIdx.x & 63;
    int n = blockIdx.x * 4 + wv;
    if (n >= N) return;
    int s0 = row_start[n], s1 = row_start[n + 1];
    int head = l >> 4;
    unsigned lb4 = (unsigned)l * 4u;       // byte offset within fp8 row (4 features/lane)
    const char* h1b = (const char*)h1f;
    float4 adv = ((const float4*)ad1)[n];
    float4 acc0 = make_float4(0, 0, 0, 0), acc1 = acc0, acc2 = acc0, acc3 = acc0;
    float den = 0.f;
    for (int c0 = s0; c0 < s1; c0 += 64) {
        int cl = min(64, s1 - c0);
        // phase 1: lane i owns edge i — coalesced id load, 1 gather, 4 exps/edge total
        if (l < cl) {
            int si = csr_src[c0 + l];
            s_src[wv][l] = si;
            float4 a = ((const float4*)as1)[si];
            float4 e;
            e.x = a.x + adv.x; e.x = e.x > 0.f ? e.x : NEG_SLOPE * e.x; e.x = __expf(e.x);
            e.y = a.y + adv.y; e.y = e.y > 0.f ? e.y : NEG_SLOPE * e.y; e.y = __expf(e.y);
            e.z = a.z + adv.z; e.z = e.z > 0.f ? e.z : NEG_SLOPE * e.z; e.z = __expf(e.z);
            e.w = a.w + adv.w; e.w = e.w > 0.f ? e.w : NEG_SLOPE * e.w; e.w = __expf(e.w);
            s_w[wv][l] = e;
        }
        // phase 2: weighted gather; src/w via LDS broadcast, 8 gathers in flight
        int p = 0;
        for (; p + 8 <= cl; p += 8) {
            int ss[8]; float ww[8]; unsigned vv[8];
#pragma unroll
            for (int i = 0; i < 8; i++) {
                ss[i] = s_src[wv][p + i];
                ww[i] = ((const float*)&s_w[wv][p + i])[head];
            }
#pragma unroll
            for (int i = 0; i < 8; i++)
                vv[i] = *(const unsigned*)(h1b + (unsigned)ss[i] * 256u + lb4);
#pragma unroll
            for (int i = 0; i < 8; i++) {
                den += ww[i];
                if ((i & 3) == 0) fma_fp8x4(acc0, ww[i], vv[i]);
                if ((i & 3) == 1) fma_fp8x4(acc1, ww[i], vv[i]);
                if ((i & 3) == 2) fma_fp8x4(acc2, ww[i], vv[i]);
                if ((i & 3) == 3) fma_fp8x4(acc3, ww[i], vv[i]);
            }
        }
        for (; p + 4 <= cl; p += 4) {
            int sA = s_src[wv][p],     sB = s_src[wv][p + 1];
            int sC = s_src[wv][p + 2], sD = s_src[wv][p + 3];
            float wA = ((const float*)&s_w[wv][p    ])[head];
            float wB = ((const float*)&s_w[wv][p + 1])[head];
            float wC = ((const float*)&s_w[wv][p + 2])[head];
            float wD = ((const float*)&s_w[wv][p + 3])[head];
            unsigned vA = *(const unsigned*)(h1b + (unsigned)sA * 256u + lb4);
            unsigned vB = *(const unsigned*)(h1b + (unsigned)sB * 256u + lb4);
            unsigned vC = *(const unsigned*)(h1b + (unsigned)sC * 256u + lb4);
            unsigned vD = *(const unsigned*)(h1b + (unsigned)sD * 256u + lb4);
            den += (wA + wB) + (wC + wD);
            fma_fp8x4(acc0, wA, vA); fma_fp8x4(acc1, wB, vB);
            fma_fp8x4(acc2, wC, vC); fma_fp8x4(acc3, wD, vD);
        }
        for (; p < cl; p++) {
            int s = s_src[wv][p];
            float wg = ((const float*)&s_w[wv][p])[head];
            unsigned v = *(const unsigned*)(h1b + (unsigned)s * 256u + lb4);
            den += wg;
            fma_fp8x4(acc0, wg, v);
        }
    }
    float4 acc;
    acc.x = (acc0.x + acc1.x) + (acc2.x + acc3.x);
    acc.y = (acc0.y + acc1.y) + (acc2.y + acc3.y);
    acc.z = (acc0.z + acc1.z) + (acc2.z + acc3.z);
    acc.w = (acc0.w + acc1.w) + (acc2.w + acc3.w);
    float inv = 1.f / den;
    float4 b = ((const float4*)b1)[l];
    float r0 = acc.x * inv + b.x; r0 = r0 > 0.f ? r0 : 0.f;
    float r1 = acc.y * inv + b.y; r1 = r1 > 0.f ? r1 : 0.f;
    float r2 = acc.z * inv + b.z; r2 = r2 > 0.f ? r2 : 0.f;
    float r3 = acc.w * inv + b.w; r3 = r3 > 0.f ? r3 : 0.f;
    unsigned short u0 = __builtin_bit_cast(unsigned short, __float2half(r0));
    unsigned short u1 = __builtin_bit_cast(unsigned short, __float2half(r1));
    unsigned short u2 = __builtin_bit_cast(unsigned short, __float2half(r2));
    unsigned short u3 = __builtin_bit_cast(unsigned short, __float2half(r3));
    uint2 st;
    st.x = (unsigned)u0 | ((unsigned)u1 << 16);
    st.y = (unsigned)u2 | ((unsigned)u3 << 16);
    *(uint2*)((char*)hbh + (unsigned)n * 512u + (unsigned)l * 8u) = st;
}

// ---------------- GEMM2 via f16 MFMA: LDS-staged A and B tiles, fused att dots ----------------
__global__ __launch_bounds__(256) void k_gemm2_mfma(const _Float16* __restrict__ hbh,
                                                    const _Float16* __restrict__ w2t,
                                                    const float* __restrict__ att_s2,
                                                    const float* __restrict__ att_d2,
                                                    __half* __restrict__ h2h,
                                                    float* __restrict__ as2, float* __restrict__ ad2, int N) {
    __shared__ _Float16 Hs[64 * LDP];
    __shared__ _Float16 Ws[48 * LDP];
    int tid = threadIdx.x;
    int row0 = blockIdx.x * 64;
#pragma unroll
    for (int it = 0; it < 8; it++) {
        int c = tid + it * 256;       // 2048 chunks of 16B
        int r = c >> 5, q = c & 31;
        uint4 v = make_uint4(0, 0, 0, 0);
        if (row0 + r < N) v = ((const uint4*)hbh)[(size_t)(row0 + r) * 32 + q];
        *(uint4*)&Hs[r * LDP + q * 8] = v;
    }
#pragma unroll
    for (int it = 0; it < 6; it++) {
        int c = tid + it * 256;       // 1536 chunks
        int r = c >> 5, q = c & 31;
        uint4 v = ((const uint4*)w2t)[c];
        *(uint4*)&Ws[r * LDP + q * 8] = v;
    }
    __syncthreads();
    int w = tid >> 6, l = tid & 63;
    int hi = l >> 4, lo = l & 15;
    f32x4 acc[3] = {};
#pragma unroll
    for (int kk = 0; kk < 8; kk++) {
        half8v a = *(const half8v*)&Hs[(16 * w + lo) * LDP + kk * 32 + 8 * hi];
#pragma unroll
        for (int jb = 0; jb < 3; jb++) {
            half8v b = *(const half8v*)&Ws[(16 * jb + lo) * LDP + kk * 32 + 8 * hi];
            acc[jb] = __builtin_amdgcn_mfma_f32_16x16x32_f16(a, b, acc[jb], 0, 0, 0);
        }
    }
    float asr[3], adr[3];
#pragma unroll
    for (int jb = 0; jb < 3; jb++) {
        int c = 16 * jb + lo;
        asr[jb] = (c < 40) ? att_s2[c] : 0.f;
        adr[jb] = (c < 40) ? att_d2[c] : 0.f;
    }
#pragma unroll
    for (int j = 0; j < 4; j++) {
        int r = row0 + 16 * w + 4 * hi + j;
        float s = 0.f, d = 0.f;
#pragma unroll
        for (int jb = 0; jb < 3; jb++) {
            float v = acc[jb][j];
            s += v * asr[jb];
            d += v * adr[jb];
            int c = 16 * jb + lo;
            if (c < 40 && r < N) h2h[(size_t)r * 40 + c] = __float2half(v);
        }
        s += __shfl_xor(s, 1); s += __shfl_xor(s, 2); s += __shfl_xor(s, 4); s += __shfl_xor(s, 8);
        d += __shfl_xor(d, 1); d += __shfl_xor(d, 2); d += __shfl_xor(d, 4); d += __shfl_xor(d, 8);
        if (lo == 0 && r < N) { as2[r] = s; ad2[r] = d; }
    }
}

// ---------------- layer2 fused softmax-aggregation + bias + log_softmax: 2-phase ----------------
__global__ __launch_bounds__(256) void k_agg2(const __half* __restrict__ h2h, const float* __restrict__ as2,
                                              const float* __restrict__ ad2, const int* __restrict__ row_start,
                                              const int* __restrict__ csr_src, const float* __restrict__ b2,
                                              float* __restrict__ out, int N) {
    __shared__ int   s_src[4][64];
    __shared__ float s_w[4][64];
    int wv = threadIdx.x >> 6, l = threadIdx.x & 63;
    int n = blockIdx.x * 4 + wv;
    if (n >= N) return;
    int s0 = row_start[n], s1 = row_start[n + 1];
    int grp = l / 20, li = l - grp * 20;     // grp 3 = lanes 60..63 idle in phase 2
    unsigned li4 = (unsigned)li * 4u;
    const char* h2b = (const char*)h2h;
    float ad = ad2[n];
    float2 accA = make_float2(0.f, 0.f), accB = accA;
    float denA = 0.f, denB = 0.f;
    bool act = grp < 3;
    for (int c0 = s0; c0 < s1; c0 += 64) {
        int cl = min(64, s1 - c0);
        if (l < cl) {
            int si = csr_src[c0 + l];
            s_src[wv][l] = si;
            float e = as2[si] + ad;
            e = e > 0.f ? e : NEG_SLOPE * e;
            s_w[wv][l] = __expf(e);
        }
        if (act) {
            int p = grp;
            for (; p + 3 < cl; p += 6) {
                int sA = s_src[wv][p], sB = s_src[wv][p + 3];
                float wA = s_w[wv][p], wB = s_w[wv][p + 3];
                unsigned vA = *(const unsigned*)(h2b + (unsigned)sA * 80u + li4);
                unsigned vB = *(const unsigned*)(h2b + (unsigned)sB * 80u + li4);
                denA += wA; denB += wB;
                float2 fA = __half22float2(__builtin_bit_cast(__half2, vA));
                float2 fB = __half22float2(__builtin_bit_cast(__half2, vB));
                accA.x += wA * fA.x; accA.y += wA * fA.y;
                accB.x += wB * fB.x; accB.y += wB * fB.y;
            }
            for (; p < cl; p += 3) {
                int si = s_src[wv][p];
                float w = s_w[wv][p];
                unsigned v = *(const unsigned*)(h2b + (unsigned)si * 80u + li4);
                denA += w;
                float2 f = __half22float2(__builtin_bit_cast(__half2, v));
                accA.x += w * f.x; accA.y += w * f.y;
            }
        }
    }
    float den = denA + denB;
    float2 acc = make_float2(accA.x + accB.x, accA.y + accB.y);
    float den_t = __shfl(den, li) + __shfl(den, 20 + li) + __shfl(den, 40 + li);
    float ax = acc.x + __shfl(acc.x, l + 20) + __shfl(acc.x, l + 40);
    float ay = acc.y + __shfl(acc.y, l + 20) + __shfl(acc.y, l + 40);
    float inv = 1.f / den_t;
    float lg0 = -1e30f, lg1 = -1e30f;
    if (l < 20) {
        lg0 = ax * inv + b2[2 * l];
        lg1 = ay * inv + b2[2 * l + 1];
    }
    float mx = fmaxf(lg0, lg1);
    for (int off = 32; off; off >>= 1) mx = fmaxf(mx, __shfl_xor(mx, off));
    float s = (l < 20) ? (__expf(lg0 - mx) + __expf(lg1 - mx)) : 0.f;
    for (int off = 32; off; off >>= 1) s += __shfl_xor(s, off);
    float ls = logf(s);
    if (l < 20) {
        out[(size_t)n * 40 + 2 * l]     = lg0 - mx - ls;
        out[(size_t)n * 40 + 2 * l + 1] = lg1 - mx - ls;
    }
}

extern "C" void kernel_launch(void* const* d_in, const int* in_sizes, int n_in,
                              void* d_out, int out_size, void* d_ws, size_t ws_size,
                              hipStream_t stream) {
    const float* x      = (const float*)d_in[0];
    const int*   ei     = (const int*)d_in[1];
    const float* W1     = (const float*)d_in[2];
    const float* att_s1 = (const float*)d_in[3];
    const float* att_d1 = (const float*)d_in[4];
    const float* b1     = (const float*)d_in[5];
    const float* W2     = (const float*)d_in[6];
    const float* att_s2 = (const float*)d_in[7];
    const float* att_d2 = (const float*)d_in[8];
    const float* b2     = (const float*)d_in[9];

    int N = in_sizes[0] / 256;
    int E = in_sizes[1] / 2;
    int Et = E + N;

    char* ws = (char*)d_ws;
    size_t off = 0;
    auto alloc = [&](size_t bytes) -> void* {
        void* p = ws + off;
        off += (bytes + 255) / 256 * 256;
        return p;
    };
    unsigned char* h1f = (unsigned char*)alloc((size_t)N * 256);   // fp8 gather table
    __half* hbh = (__half*)alloc((size_t)N * 256 * 2);
    __half* h2h = (__half*)alloc((size_t)N * 40 * 2);
    unsigned short* w1t = (unsigned short*)alloc((size_t)256 * 256 * 2);
    __half* w2t = (__half*)alloc((size_t)48 * 256 * 2);
    float* as1 = (float*)alloc((size_t)N * 4 * 4);
    float* ad1 = (float*)alloc((size_t)N * 4 * 4);
    float* as2 = (float*)alloc((size_t)N * 4);
    float* ad2 = (float*)alloc((size_t)N * 4);
    int* deg       = (int*)alloc((size_t)N * 4);
    int* rank      = (int*)alloc((size_t)Et * 4);
    int* row_start = (int*)alloc((size_t)(N + 1) * 4);
    int* csr_src   = (int*)alloc((size_t)Et * 4);
    int NB = (N + 255) / 256;
    int* bsums = (int*)alloc((size_t)NB * 4);

    hipMemsetAsync(deg, 0, (size_t)N * 4, stream);

    int degB = (Et + 255) / 256;
    k_deg_cvt<<<degB + 304, 256, 0, stream>>>(ei, E, N, degB, deg, rank, W1, W2, w1t, w2t);
    k_scan_block<<<NB, 256, 0, stream>>>(deg, N, row_start, bsums);
    k_scan_add<<<NB, 256, 0, stream>>>(row_start, bsums, N, Et, NB);
    k_scatter<<<degB, 256, 0, stream>>>(ei, rank, E, N, row_start, csr_src);

    dim3 g1((N + 63) / 64, 4);
    k_gemm1_mfma<<<g1, 256, 0, stream>>>(x, w1t, att_s1, att_d1, h1f, as1, ad1, N);
    k_agg1<<<(N + 3) / 4, 256, 0, stream>>>(h1f, as1, ad1, row_start, csr_src, b1, hbh, N);
    k_gemm2_mfma<<<(N + 63) / 64, 256, 0, stream>>>((const _Float16*)hbh, (const _Float16*)w2t,
                                                    att_s2, att_d2, h2h, as2, ad2, N);
    k_agg2<<<(N + 3) / 4, 256, 0, stream>>>(h2h, as2, ad2, row_start, csr_src, b2, (float*)d_out, N);
}

// Round 20
// 178.681 us; speedup vs baseline: 1.0114x; 1.0114x over previous
//
#include <hip/hip_runtime.h>
#include <hip/hip_fp16.h>
#include <hip/hip_fp8.h>
#include <math.h>

#define NEG_SLOPE 0.2f

typedef short short8v __attribute__((ext_vector_type(8)));
typedef _Float16 half8v __attribute__((ext_vector_type(8)));
typedef float f32x4 __attribute__((ext_vector_type(4)));
typedef float f32x2 __attribute__((ext_vector_type(2)));

__device__ __forceinline__ unsigned short f2bf(float f) {
    unsigned int u = __builtin_bit_cast(unsigned int, f);
    u += 0x7FFFu + ((u >> 16) & 1u);   // RNE
    return (unsigned short)(u >> 16);
}

__device__ __forceinline__ unsigned char f2fp8(float f) {
    __hip_fp8_e4m3 q(f);
    return (unsigned char)q.__x;
}

__device__ __forceinline__ float fp82f(unsigned char b) {
    __hip_fp8_e4m3 q;
    q.__x = (__hip_fp8_storage_t)b;
    return (float)q;
}

// hardware packed fp8->f32 decode (OCP e4m3 on gfx950); 2 instrs per 4 bytes
__device__ __forceinline__ void fma_fp8x4(float4& acc, float w, unsigned v) {
#if __has_builtin(__builtin_amdgcn_cvt_pk_f32_fp8)
    f32x2 lo2 = __builtin_amdgcn_cvt_pk_f32_fp8(v, false);   // bytes 0,1
    f32x2 hi2 = __builtin_amdgcn_cvt_pk_f32_fp8(v, true);    // bytes 2,3
    acc.x += w * lo2[0];
    acc.y += w * lo2[1];
    acc.z += w * hi2[0];
    acc.w += w * hi2[1];
#else
    acc.x += w * fp82f((unsigned char)(v & 0xffu));
    acc.y += w * fp82f((unsigned char)((v >> 8) & 0xffu));
    acc.z += w * fp82f((unsigned char)((v >> 16) & 0xffu));
    acc.w += w * fp82f((unsigned char)(v >> 24));
#endif
}

// ---------------- CSR build: degree count + weight converts (merged) ----------------
__global__ void k_deg_cvt(const int* __restrict__ ei, int E, int N, int degB,
                          int* __restrict__ deg, int* __restrict__ rank,
                          const float* __restrict__ W1, const float* __restrict__ W2,
                          unsigned short* __restrict__ w1t, __half* __restrict__ w2t) {
    int b = blockIdx.x;
    if (b < degB) {
        int i = b * 256 + threadIdx.x;
        int Et = E + N;
        if (i >= Et) return;
        int dst = (i < E) ? ei[E + i] : (i - E);
        rank[i] = atomicAdd(&deg[dst], 1);
    } else {
        int bb = b - degB;
        int k = threadIdx.x;
        if (bb < 256) {
            w1t[bb * 256 + k] = f2bf(W1[k * 256 + bb]);
        } else {
            int c = bb - 256;
            w2t[c * 256 + k] = __float2half((c < 40) ? W2[k * 40 + c] : 0.f);
        }
    }
}

__global__ void k_scan_block(const int* __restrict__ deg, int N, int* __restrict__ excl, int* __restrict__ bsums) {
    __shared__ int s[256];
    int b = blockIdx.x, t = threadIdx.x;
    int i = b * 256 + t;
    int v = (i < N) ? deg[i] : 0;
    s[t] = v;
    __syncthreads();
    for (int off = 1; off < 256; off <<= 1) {
        int add = (t >= off) ? s[t - off] : 0;
        __syncthreads();
        s[t] += add;
        __syncthreads();
    }
    int incl = s[t];
    if (i < N) excl[i] = incl - v;
    if (t == 255) bsums[b] = incl;
}

// fused: each block reduces bsums[0..b) (NB<=256) then adds to its row_start slice
__global__ void k_scan_add(int* __restrict__ row_start, const int* __restrict__ bsums,
                           int N, int Et, int NB) {
    __shared__ int ws[4];
    int b = blockIdx.x, t = threadIdx.x;
    int wv = t >> 6, l = t & 63;
    int v = (t < b && t < NB) ? bsums[t] : 0;
    for (int off = 32; off; off >>= 1) v += __shfl_xor(v, off);
    if (l == 0) ws[wv] = v;
    __syncthreads();
    int total = ws[0] + ws[1] + ws[2] + ws[3];
    int i = b * 256 + t;
    if (i < N) row_start[i] += total;
    if (i == 0) row_start[N] = Et;
}

__global__ void k_scatter(const int* __restrict__ ei, const int* __restrict__ rank, int E, int N,
                          const int* __restrict__ row_start, int* __restrict__ csr_src) {
    int i = blockIdx.x * blockDim.x + threadIdx.x;
    int Et = E + N;
    if (i >= Et) return;
    int src, dst;
    if (i < E) { src = ei[i]; dst = ei[E + i]; }
    else       { src = i - E; dst = i - E; }
    csr_src[row_start[dst] + rank[i]] = src;
}

// ---------------- GEMM1 MFMA: coalesced A staging, single 33KB buffer reused A->B, no prefetch ----------------
// writes h1 gather table as fp8 e4m3 (row-major [N][256] bytes); 4 blocks/CU
#define LDP 264
__global__ __launch_bounds__(256) void k_gemm1_mfma(const float* __restrict__ x,
                                                    const unsigned short* __restrict__ w1t,
                                                    const float* __restrict__ att_s,
                                                    const float* __restrict__ att_d,
                                                    unsigned char* __restrict__ h1f,
                                                    float* __restrict__ as1, float* __restrict__ ad1, int N) {
    __shared__ unsigned short Sb[64 * LDP];
    int tid = threadIdx.x;
    int row0 = blockIdx.x * 64;
    // stage A coalesced with fused f32->bf16 convert (x read once per block)
#pragma unroll
    for (int it = 0; it < 16; it++) {
        int c = tid + it * 256;        // 4096 chunks of 4 floats
        int r = c >> 6, q = c & 63;
        float4 v = make_float4(0, 0, 0, 0);
        if (row0 + r < N) v = ((const float4*)x)[(size_t)(row0 + r) * 64 + q];
        ushort4 o;
        o.x = f2bf(v.x); o.y = f2bf(v.y); o.z = f2bf(v.z); o.w = f2bf(v.w);
        *(ushort4*)&Sb[r * LDP + q * 4] = o;
    }
    __syncthreads();                   // A staged
    int w = tid >> 6, l = tid & 63;
    int hi = l >> 4, lo = l & 15;
    // hoist A fragments (head-invariant) to registers; Sb then becomes the B buffer
    short8v a[8];
#pragma unroll
    for (int kk = 0; kk < 8; kk++)
        a[kk] = *(const short8v*)&Sb[(16 * w + lo) * LDP + kk * 32 + 8 * hi];
    __syncthreads();                   // all waves done reading A
    for (int head = 0; head < 4; head++) {
        // stage B[head] coalesced (short-lived temps only — no prefetch arrays)
#pragma unroll
        for (int it = 0; it < 8; it++) {
            int c = tid + it * 256;
            int r = c >> 5, q = c & 31;
            uint4 vb = ((const uint4*)w1t)[(size_t)(head * 64 + r) * 32 + q];
            *(uint4*)&Sb[r * LDP + q * 8] = vb;
        }
        __syncthreads();               // B ready
        f32x4 acc[4] = {};
#pragma unroll
        for (int kk = 0; kk < 8; kk++) {
#pragma unroll
            for (int jb = 0; jb < 4; jb++) {
                short8v b = *(const short8v*)&Sb[(16 * jb + lo) * LDP + kk * 32 + 8 * hi];
                acc[jb] = __builtin_amdgcn_mfma_f32_16x16x32_bf16(a[kk], b, acc[jb], 0, 0, 0);
            }
        }
        float asr[4], adr[4];
#pragma unroll
        for (int jb = 0; jb < 4; jb++) {
            int c = head * 64 + lo + 16 * jb;
            asr[jb] = att_s[c];
            adr[jb] = att_d[c];
        }
#pragma unroll
        for (int j = 0; j < 4; j++) {
            int rr = 16 * w + 4 * hi + j;
            int r = row0 + rr;
            float s = 0.f, d = 0.f;
#pragma unroll
            for (int jb = 0; jb < 4; jb++) {
                float v = acc[jb][j];
                s += v * asr[jb];
                d += v * adr[jb];
                if (r < N) h1f[(size_t)r * 256 + head * 64 + lo + 16 * jb] = f2fp8(v);
            }
            s += __shfl_xor(s, 1); s += __shfl_xor(s, 2); s += __shfl_xor(s, 4); s += __shfl_xor(s, 8);
            d += __shfl_xor(d, 1); d += __shfl_xor(d, 2); d += __shfl_xor(d, 4); d += __shfl_xor(d, 8);
            if (lo == 0 && r < N) {
                as1[r * 4 + head] = s;
                ad1[r * 4 + head] = d;
            }
        }
        if (head < 3) __syncthreads();   // before Sb overwrite
    }
}

// ---------------- layer1 fused softmax-aggregation: 2-phase, 8-deep gather unroll, fp8 table ----------------
__global__ __launch_bounds__(256) void k_agg1(const unsigned char* __restrict__ h1f, const float* __restrict__ as1,
                                              const float* __restrict__ ad1, const int* __restrict__ row_start,
                                              const int* __restrict__ csr_src, const float* __restrict__ b1,
                                              __half* __restrict__ hbh, int N) {
    __shared__ int    s_src[4][64];
    __shared__ float4 s_w[4][64];
    int wv = threadIdx.x >> 6, l = threadIdx.x & 63;
    int n = blockIdx.x * 4 + wv;
    if (n >= N) return;
    int s0 = row_start[n], s1 = row_start[n + 1];
    int head = l >> 4;
    unsigned lb4 = (unsigned)l * 4u;       // byte offset within fp8 row (4 features/lane)
    const char* h1b = (const char*)h1f;
    float4 adv = ((const float4*)ad1)[n];
    float4 acc0 = make_float4(0, 0, 0, 0), acc1 = acc0, acc2 = acc0, acc3 = acc0;
    float den = 0.f;
    for (int c0 = s0; c0 < s1; c0 += 64) {
        int cl = min(64, s1 - c0);
        // phase 1: lane i owns edge i — coalesced id load, 1 gather, 4 exps/edge total
        if (l < cl) {
            int si = csr_src[c0 + l];
            s_src[wv][l] = si;
            float4 a = ((const float4*)as1)[si];
            float4 e;
            e.x = a.x + adv.x; e.x = e.x > 0.f ? e.x : NEG_SLOPE * e.x; e.x = __expf(e.x);
            e.y = a.y + adv.y; e.y = e.y > 0.f ? e.y : NEG_SLOPE * e.y; e.y = __expf(e.y);
            e.z = a.z + adv.z; e.z = e.z > 0.f ? e.z : NEG_SLOPE * e.z; e.z = __expf(e.z);
            e.w = a.w + adv.w; e.w = e.w > 0.f ? e.w : NEG_SLOPE * e.w; e.w = __expf(e.w);
            s_w[wv][l] = e;
        }
        // phase 2: weighted gather; src/w via LDS broadcast, 8 gathers in flight
        int p = 0;
        for (; p + 8 <= cl; p += 8) {
            int ss[8]; float ww[8]; unsigned vv[8];
#pragma unroll
            for (int i = 0; i < 8; i++) {
                ss[i] = s_src[wv][p + i];
                ww[i] = ((const float*)&s_w[wv][p + i])[head];
            }
#pragma unroll
            for (int i = 0; i < 8; i++)
                vv[i] = *(const unsigned*)(h1b + (unsigned)ss[i] * 256u + lb4);
#pragma unroll
            for (int i = 0; i < 8; i++) {
                den += ww[i];
                if ((i & 3) == 0) fma_fp8x4(acc0, ww[i], vv[i]);
                if ((i & 3) == 1) fma_fp8x4(acc1, ww[i], vv[i]);
                if ((i & 3) == 2) fma_fp8x4(acc2, ww[i], vv[i]);
                if ((i & 3) == 3) fma_fp8x4(acc3, ww[i], vv[i]);
            }
        }
        for (; p + 4 <= cl; p += 4) {
            int sA = s_src[wv][p],     sB = s_src[wv][p + 1];
            int sC = s_src[wv][p + 2], sD = s_src[wv][p + 3];
            float wA = ((const float*)&s_w[wv][p    ])[head];
            float wB = ((const float*)&s_w[wv][p + 1])[head];
            float wC = ((const float*)&s_w[wv][p + 2])[head];
            float wD = ((const float*)&s_w[wv][p + 3])[head];
            unsigned vA = *(const unsigned*)(h1b + (unsigned)sA * 256u + lb4);
            unsigned vB = *(const unsigned*)(h1b + (unsigned)sB * 256u + lb4);
            unsigned vC = *(const unsigned*)(h1b + (unsigned)sC * 256u + lb4);
            unsigned vD = *(const unsigned*)(h1b + (unsigned)sD * 256u + lb4);
            den += (wA + wB) + (wC + wD);
            fma_fp8x4(acc0, wA, vA); fma_fp8x4(acc1, wB, vB);
            fma_fp8x4(acc2, wC, vC); fma_fp8x4(acc3, wD, vD);
        }
        for (; p < cl; p++) {
            int s = s_src[wv][p];
            float wg = ((const float*)&s_w[wv][p])[head];
            unsigned v = *(const unsigned*)(h1b + (unsigned)s * 256u + lb4);
            den += wg;
            fma_fp8x4(acc0, wg, v);
        }
    }
    float4 acc;
    acc.x = (acc0.x + acc1.x) + (acc2.x + acc3.x);
    acc.y = (acc0.y + acc1.y) + (acc2.y + acc3.y);
    acc.z = (acc0.z + acc1.z) + (acc2.z + acc3.z);
    acc.w = (acc0.w + acc1.w) + (acc2.w + acc3.w);
    float inv = 1.f / den;
    float4 b = ((const float4*)b1)[l];
    float r0 = acc.x * inv + b.x; r0 = r0 > 0.f ? r0 : 0.f;
    float r1 = acc.y * inv + b.y; r1 = r1 > 0.f ? r1 : 0.f;
    float r2 = acc.z * inv + b.z; r2 = r2 > 0.f ? r2 : 0.f;
    float r3 = acc.w * inv + b.w; r3 = r3 > 0.f ? r3 : 0.f;
    unsigned short u0 = __builtin_bit_cast(unsigned short, __float2half(r0));
    unsigned short u1 = __builtin_bit_cast(unsigned short, __float2half(r1));
    unsigned short u2 = __builtin_bit_cast(unsigned short, __float2half(r2));
    unsigned short u3 = __builtin_bit_cast(unsigned short, __float2half(r3));
    uint2 st;
    st.x = (unsigned)u0 | ((unsigned)u1 << 16);
    st.y = (unsigned)u2 | ((unsigned)u3 << 16);
    *(uint2*)((char*)hbh + (unsigned)n * 512u + (unsigned)l * 8u) = st;
}

// ---------------- GEMM2 via f16 MFMA: LDS-staged A and B tiles, fused att dots ----------------
__global__ __launch_bounds__(256) void k_gemm2_mfma(const _Float16* __restrict__ hbh,
                                                    const _Float16* __restrict__ w2t,
                                                    const float* __restrict__ att_s2,
                                                    const float* __restrict__ att_d2,
                                                    __half* __restrict__ h2h,
                                                    float* __restrict__ as2, float* __restrict__ ad2, int N) {
    __shared__ _Float16 Hs[64 * LDP];
    __shared__ _Float16 Ws[48 * LDP];
    int tid = threadIdx.x;
    int row0 = blockIdx.x * 64;
#pragma unroll
    for (int it = 0; it < 8; it++) {
        int c = tid + it * 256;       // 2048 chunks of 16B
        int r = c >> 5, q = c & 31;
        uint4 v = make_uint4(0, 0, 0, 0);
        if (row0 + r < N) v = ((const uint4*)hbh)[(size_t)(row0 + r) * 32 + q];
        *(uint4*)&Hs[r * LDP + q * 8] = v;
    }
#pragma unroll
    for (int it = 0; it < 6; it++) {
        int c = tid + it * 256;       // 1536 chunks
        int r = c >> 5, q = c & 31;
        uint4 v = ((const uint4*)w2t)[c];
        *(uint4*)&Ws[r * LDP + q * 8] = v;
    }
    __syncthreads();
    int w = tid >> 6, l = tid & 63;
    int hi = l >> 4, lo = l & 15;
    f32x4 acc[3] = {};
#pragma unroll
    for (int kk = 0; kk < 8; kk++) {
        half8v a = *(const half8v*)&Hs[(16 * w + lo) * LDP + kk * 32 + 8 * hi];
#pragma unroll
        for (int jb = 0; jb < 3; jb++) {
            half8v b = *(const half8v*)&Ws[(16 * jb + lo) * LDP + kk * 32 + 8 * hi];
            acc[jb] = __builtin_amdgcn_mfma_f32_16x16x32_f16(a, b, acc[jb], 0, 0, 0);
        }
    }
    float asr[3], adr[3];
#pragma unroll
    for (int jb = 0; jb < 3; jb++) {
        int c = 16 * jb + lo;
        asr[jb] = (c < 40) ? att_s2[c] : 0.f;
        adr[jb] = (c < 40) ? att_d2[c] : 0.f;
    }
#pragma unroll
    for (int j = 0; j < 4; j++) {
        int r = row0 + 16 * w + 4 * hi + j;
        float s = 0.f, d = 0.f;
#pragma unroll
        for (int jb = 0; jb < 3; jb++) {
            float v = acc[jb][j];
            s += v * asr[jb];
            d += v * adr[jb];
            int c = 16 * jb + lo;
            if (c < 40 && r < N) h2h[(size_t)r * 40 + c] = __float2half(v);
        }
        s += __shfl_xor(s, 1); s += __shfl_xor(s, 2); s += __shfl_xor(s, 4); s += __shfl_xor(s, 8);
        d += __shfl_xor(d, 1); d += __shfl_xor(d, 2); d += __shfl_xor(d, 4); d += __shfl_xor(d, 8);
        if (lo == 0 && r < N) { as2[r] = s; ad2[r] = d; }
    }
}

// ---------------- layer2 fused softmax-aggregation + bias + log_softmax: 2-phase ----------------
__global__ __launch_bounds__(256) void k_agg2(const __half* __restrict__ h2h, const float* __restrict__ as2,
                                              const float* __restrict__ ad2, const int* __restrict__ row_start,
                                              const int* __restrict__ csr_src, const float* __restrict__ b2,
                                              float* __restrict__ out, int N) {
    __shared__ int   s_src[4][64];
    __shared__ float s_w[4][64];
    int wv = threadIdx.x >> 6, l = threadIdx.x & 63;
    int n = blockIdx.x * 4 + wv;
    if (n >= N) return;
    int s0 = row_start[n], s1 = row_start[n + 1];
    int grp = l / 20, li = l - grp * 20;     // grp 3 = lanes 60..63 idle in phase 2
    unsigned li4 = (unsigned)li * 4u;
    const char* h2b = (const char*)h2h;
    float ad = ad2[n];
    float2 accA = make_float2(0.f, 0.f), accB = accA;
    float denA = 0.f, denB = 0.f;
    bool act = grp < 3;
    for (int c0 = s0; c0 < s1; c0 += 64) {
        int cl = min(64, s1 - c0);
        if (l < cl) {
            int si = csr_src[c0 + l];
            s_src[wv][l] = si;
            float e = as2[si] + ad;
            e = e > 0.f ? e : NEG_SLOPE * e;
            s_w[wv][l] = __expf(e);
        }
        if (act) {
            int p = grp;
            for (; p + 3 < cl; p += 6) {
                int sA = s_src[wv][p], sB = s_src[wv][p + 3];
                float wA = s_w[wv][p], wB = s_w[wv][p + 3];
                unsigned vA = *(const unsigned*)(h2b + (unsigned)sA * 80u + li4);
                unsigned vB = *(const unsigned*)(h2b + (unsigned)sB * 80u + li4);
                denA += wA; denB += wB;
                float2 fA = __half22float2(__builtin_bit_cast(__half2, vA));
                float2 fB = __half22float2(__builtin_bit_cast(__half2, vB));
                accA.x += wA * fA.x; accA.y += wA * fA.y;
                accB.x += wB * fB.x; accB.y += wB * fB.y;
            }
            for (; p < cl; p += 3) {
                int si = s_src[wv][p];
                float w = s_w[wv][p];
                unsigned v = *(const unsigned*)(h2b + (unsigned)si * 80u + li4);
                denA += w;
                float2 f = __half22float2(__builtin_bit_cast(__half2, v));
                accA.x += w * f.x; accA.y += w * f.y;
            }
        }
    }
    float den = denA + denB;
    float2 acc = make_float2(accA.x + accB.x, accA.y + accB.y);
    float den_t = __shfl(den, li) + __shfl(den, 20 + li) + __shfl(den, 40 + li);
    float ax = acc.x + __shfl(acc.x, l + 20) + __shfl(acc.x, l + 40);
    float ay = acc.y + __shfl(acc.y, l + 20) + __shfl(acc.y, l + 40);
    float inv = 1.f / den_t;
    float lg0 = -1e30f, lg1 = -1e30f;
    if (l < 20) {
        lg0 = ax * inv + b2[2 * l];
        lg1 = ay * inv + b2[2 * l + 1];
    }
    float mx = fmaxf(lg0, lg1);
    for (int off = 32; off; off >>= 1) mx = fmaxf(mx, __shfl_xor(mx, off));
    float s = (l < 20) ? (__expf(lg0 - mx) + __expf(lg1 - mx)) : 0.f;
    for (int off = 32; off; off >>= 1) s += __shfl_xor(s, off);
    float ls = logf(s);
    if (l < 20) {
        out[(size_t)n * 40 + 2 * l]     = lg0 - mx - ls;
        out[(size_t)n * 40 + 2 * l + 1] = lg1 - mx - ls;
    }
}

extern "C" void kernel_launch(void* const* d_in, const int* in_sizes, int n_in,
                              void* d_out, int out_size, void* d_ws, size_t ws_size,
                              hipStream_t stream) {
    const float* x      = (const float*)d_in[0];
    const int*   ei     = (const int*)d_in[1];
    const float* W1     = (const float*)d_in[2];
    const float* att_s1 = (const float*)d_in[3];
    const float* att_d1 = (const float*)d_in[4];
    const float* b1     = (const float*)d_in[5];
    const float* W2     = (const float*)d_in[6];
    const float* att_s2 = (const float*)d_in[7];
    const float* att_d2 = (const float*)d_in[8];
    const float* b2     = (const float*)d_in[9];

    int N = in_sizes[0] / 256;
    int E = in_sizes[1] / 2;
    int Et = E + N;

    char* ws = (char*)d_ws;
    size_t off = 0;
    auto alloc = [&](size_t bytes) -> void* {
        void* p = ws + off;
        off += (bytes + 255) / 256 * 256;
        return p;
    };
    unsigned char* h1f = (unsigned char*)alloc((size_t)N * 256);   // fp8 gather table
    __half* hbh = (__half*)alloc((size_t)N * 256 * 2);
    __half* h2h = (__half*)alloc((size_t)N * 40 * 2);
    unsigned short* w1t = (unsigned short*)alloc((size_t)256 * 256 * 2);
    __half* w2t = (__half*)alloc((size_t)48 * 256 * 2);
    float* as1 = (float*)alloc((size_t)N * 4 * 4);
    float* ad1 = (float*)alloc((size_t)N * 4 * 4);
    float* as2 = (float*)alloc((size_t)N * 4);
    float* ad2 = (float*)alloc((size_t)N * 4);
    int* deg       = (int*)alloc((size_t)N * 4);
    int* rank      = (int*)alloc((size_t)Et * 4);
    int* row_start = (int*)alloc((size_t)(N + 1) * 4);
    int* csr_src   = (int*)alloc((size_t)Et * 4);
    int NB = (N + 255) / 256;
    int* bsums = (int*)alloc((size_t)NB * 4);

    hipMemsetAsync(deg, 0, (size_t)N * 4, stream);

    int degB = (Et + 255) / 256;
    k_deg_cvt<<<degB + 304, 256, 0, stream>>>(ei, E, N, degB, deg, rank, W1, W2, w1t, w2t);
    k_scan_block<<<NB, 256, 0, stream>>>(deg, N, row_start, bsums);
    k_scan_add<<<NB, 256, 0, stream>>>(row_start, bsums, N, Et, NB);
    k_scatter<<<degB, 256, 0, stream>>>(ei, rank, E, N, row_start, csr_src);

    k_gemm1_mfma<<<(N + 63) / 64, 256, 0, stream>>>(x, w1t, att_s1, att_d1, h1f, as1, ad1, N);
    k_agg1<<<(N + 3) / 4, 256, 0, stream>>>(h1f, as1, ad1, row_start, csr_src, b1, hbh, N);
    k_gemm2_mfma<<<(N + 63) / 64, 256, 0, stream>>>((const _Float16*)hbh, (const _Float16*)w2t,
                                                    att_s2, att_d2, h2h, as2, ad2, N);
    k_agg2<<<(N + 3) / 4, 256, 0, stream>>>(h2h, as2, ad2, row_start, csr_src, b2, (float*)d_out, N);
}

// Round 21
// 175.384 us; speedup vs baseline: 1.0304x; 1.0188x over previous
//
#include <hip/hip_runtime.h>
#include <hip/hip_fp16.h>
#include <hip/hip_fp8.h>
#include <math.h>

#define NEG_SLOPE 0.2f

typedef short short8v __attribute__((ext_vector_type(8)));
typedef _Float16 half8v __attribute__((ext_vector_type(8)));
typedef float f32x4 __attribute__((ext_vector_type(4)));
typedef float f32x2 __attribute__((ext_vector_type(2)));

__device__ __forceinline__ unsigned short f2bf(float f) {
    unsigned int u = __builtin_bit_cast(unsigned int, f);
    u += 0x7FFFu + ((u >> 16) & 1u);   // RNE
    return (unsigned short)(u >> 16);
}

__device__ __forceinline__ unsigned char f2fp8(float f) {
    __hip_fp8_e4m3 q(f);
    return (unsigned char)q.__x;
}

__device__ __forceinline__ float fp82f(unsigned char b) {
    __hip_fp8_e4m3 q;
    q.__x = (__hip_fp8_storage_t)b;
    return (float)q;
}

// hardware packed fp8->f32 decode (OCP e4m3 on gfx950); 2 instrs per 4 bytes
__device__ __forceinline__ void fma_fp8x4(float4& acc, float w, unsigned v) {
#if __has_builtin(__builtin_amdgcn_cvt_pk_f32_fp8)
    f32x2 lo2 = __builtin_amdgcn_cvt_pk_f32_fp8(v, false);   // bytes 0,1
    f32x2 hi2 = __builtin_amdgcn_cvt_pk_f32_fp8(v, true);    // bytes 2,3
    acc.x += w * lo2[0];
    acc.y += w * lo2[1];
    acc.z += w * hi2[0];
    acc.w += w * hi2[1];
#else
    acc.x += w * fp82f((unsigned char)(v & 0xffu));
    acc.y += w * fp82f((unsigned char)((v >> 8) & 0xffu));
    acc.z += w * fp82f((unsigned char)((v >> 16) & 0xffu));
    acc.w += w * fp82f((unsigned char)(v >> 24));
#endif
}

// ---------------- CSR build: degree count + weight converts (merged) ----------------
__global__ void k_deg_cvt(const int* __restrict__ ei, int E, int N, int degB,
                          int* __restrict__ deg, int* __restrict__ rank,
                          const float* __restrict__ W1, const float* __restrict__ W2,
                          unsigned short* __restrict__ w1t, __half* __restrict__ w2t) {
    int b = blockIdx.x;
    if (b < degB) {
        int i = b * 256 + threadIdx.x;
        int Et = E + N;
        if (i >= Et) return;
        int dst = (i < E) ? ei[E + i] : (i - E);
        rank[i] = atomicAdd(&deg[dst], 1);
    } else {
        int bb = b - degB;
        int k = threadIdx.x;
        if (bb < 256) {
            w1t[bb * 256 + k] = f2bf(W1[k * 256 + bb]);
        } else {
            int c = bb - 256;
            w2t[c * 256 + k] = __float2half((c < 40) ? W2[k * 40 + c] : 0.f);
        }
    }
}

__global__ void k_scan_block(const int* __restrict__ deg, int N, int* __restrict__ excl, int* __restrict__ bsums) {
    __shared__ int s[256];
    int b = blockIdx.x, t = threadIdx.x;
    int i = b * 256 + t;
    int v = (i < N) ? deg[i] : 0;
    s[t] = v;
    __syncthreads();
    for (int off = 1; off < 256; off <<= 1) {
        int add = (t >= off) ? s[t - off] : 0;
        __syncthreads();
        s[t] += add;
        __syncthreads();
    }
    int incl = s[t];
    if (i < N) excl[i] = incl - v;
    if (t == 255) bsums[b] = incl;
}

// fused: each block reduces bsums[0..b) (NB<=256) then adds to its row_start slice
__global__ void k_scan_add(int* __restrict__ row_start, const int* __restrict__ bsums,
                           int N, int Et, int NB) {
    __shared__ int ws[4];
    int b = blockIdx.x, t = threadIdx.x;
    int wv = t >> 6, l = t & 63;
    int v = (t < b && t < NB) ? bsums[t] : 0;
    for (int off = 32; off; off >>= 1) v += __shfl_xor(v, off);
    if (l == 0) ws[wv] = v;
    __syncthreads();
    int total = ws[0] + ws[1] + ws[2] + ws[3];
    int i = b * 256 + t;
    if (i < N) row_start[i] += total;
    if (i == 0) row_start[N] = Et;
}

__global__ void k_scatter(const int* __restrict__ ei, const int* __restrict__ rank, int E, int N,
                          const int* __restrict__ row_start, int* __restrict__ csr_src) {
    int i = blockIdx.x * blockDim.x + threadIdx.x;
    int Et = E + N;
    if (i >= Et) return;
    int src, dst;
    if (i < E) { src = ei[i]; dst = ei[E + i]; }
    else       { src = i - E; dst = i - E; }
    csr_src[row_start[dst] + rank[i]] = src;
}

// ---------------- GEMM1 MFMA: A fragments direct from global x (no As LDS); Bs-only LDS ----------------
// writes h1 gather table as fp8 e4m3 (row-major [N][256] bytes); 33KB LDS -> 4 blocks/CU
#define LDP 264
__global__ __launch_bounds__(256) void k_gemm1_mfma(const float* __restrict__ x,
                                                    const unsigned short* __restrict__ w1t,
                                                    const float* __restrict__ att_s,
                                                    const float* __restrict__ att_d,
                                                    unsigned char* __restrict__ h1f,
                                                    float* __restrict__ as1, float* __restrict__ ad1, int N) {
    __shared__ unsigned short Bs[64 * LDP];
    int tid = threadIdx.x;
    int row0 = blockIdx.x * 64;
    int w = tid >> 6, l = tid & 63;
    int hi = l >> 4, lo = l & 15;
    // A fragments: lane owns row row0+16w+lo, features kk*32+8*hi..+7 — load direct from x, cvt to bf16
    int arow = row0 + 16 * w + lo;
    bool rowok = arow < N;
    size_t xbase = (size_t)(rowok ? arow : 0) * 64;   // in float4 units
    short8v a[8];
#pragma unroll
    for (int kk = 0; kk < 8; kk++) {
        float4 f0 = make_float4(0, 0, 0, 0), f1 = f0;
        if (rowok) {
            f0 = ((const float4*)x)[xbase + kk * 8 + 2 * hi];
            f1 = ((const float4*)x)[xbase + kk * 8 + 2 * hi + 1];
        }
        short8v av;
        av[0] = (short)f2bf(f0.x); av[1] = (short)f2bf(f0.y);
        av[2] = (short)f2bf(f0.z); av[3] = (short)f2bf(f0.w);
        av[4] = (short)f2bf(f1.x); av[5] = (short)f2bf(f1.y);
        av[6] = (short)f2bf(f1.z); av[7] = (short)f2bf(f1.w);
        a[kk] = av;
    }
    for (int head = 0; head < 4; head++) {
#pragma unroll
        for (int it = 0; it < 8; it++) {
            int c = tid + it * 256;
            int r = c >> 5, q = c & 31;
            uint4 vb = ((const uint4*)w1t)[(size_t)(head * 64 + r) * 32 + q];
            *(uint4*)&Bs[r * LDP + q * 8] = vb;
        }
        __syncthreads();               // Bs ready
        f32x4 acc[4] = {};
#pragma unroll
        for (int kk = 0; kk < 8; kk++) {
#pragma unroll
            for (int jb = 0; jb < 4; jb++) {
                short8v b = *(const short8v*)&Bs[(16 * jb + lo) * LDP + kk * 32 + 8 * hi];
                acc[jb] = __builtin_amdgcn_mfma_f32_16x16x32_bf16(a[kk], b, acc[jb], 0, 0, 0);
            }
        }
        float asr[4], adr[4];
#pragma unroll
        for (int jb = 0; jb < 4; jb++) {
            int c = head * 64 + lo + 16 * jb;
            asr[jb] = att_s[c];
            adr[jb] = att_d[c];
        }
#pragma unroll
        for (int j = 0; j < 4; j++) {
            int rr = 16 * w + 4 * hi + j;
            int r = row0 + rr;
            float s = 0.f, d = 0.f;
#pragma unroll
            for (int jb = 0; jb < 4; jb++) {
                float v = acc[jb][j];
                s += v * asr[jb];
                d += v * adr[jb];
                if (r < N) h1f[(size_t)r * 256 + head * 64 + lo + 16 * jb] = f2fp8(v);
            }
            s += __shfl_xor(s, 1); s += __shfl_xor(s, 2); s += __shfl_xor(s, 4); s += __shfl_xor(s, 8);
            d += __shfl_xor(d, 1); d += __shfl_xor(d, 2); d += __shfl_xor(d, 4); d += __shfl_xor(d, 8);
            if (lo == 0 && r < N) {
                as1[r * 4 + head] = s;
                ad1[r * 4 + head] = d;
            }
        }
        if (head < 3) __syncthreads();   // before Bs overwrite
    }
}

// ---------------- layer1 fused softmax-aggregation: 2-phase, 8-deep gather unroll, fp8 table ----------------
__global__ __launch_bounds__(256) void k_agg1(const unsigned char* __restrict__ h1f, const float* __restrict__ as1,
                                              const float* __restrict__ ad1, const int* __restrict__ row_start,
                                              const int* __restrict__ csr_src, const float* __restrict__ b1,
                                              __half* __restrict__ hbh, int N) {
    __shared__ int    s_src[4][64];
    __shared__ float4 s_w[4][64];
    int wv = threadIdx.x >> 6, l = threadIdx.x & 63;
    int n = blockIdx.x * 4 + wv;
    if (n >= N) return;
    int s0 = row_start[n], s1 = row_start[n + 1];
    int head = l >> 4;
    unsigned lb4 = (unsigned)l * 4u;       // byte offset within fp8 row (4 features/lane)
    const char* h1b = (const char*)h1f;
    float4 adv = ((const float4*)ad1)[n];
    float4 acc0 = make_float4(0, 0, 0, 0), acc1 = acc0, acc2 = acc0, acc3 = acc0;
    float den = 0.f;
    for (int c0 = s0; c0 < s1; c0 += 64) {
        int cl = min(64, s1 - c0);
        // phase 1: lane i owns edge i — coalesced id load, 1 gather, 4 exps/edge total
        if (l < cl) {
            int si = csr_src[c0 + l];
            s_src[wv][l] = si;
            float4 a = ((const float4*)as1)[si];
            float4 e;
            e.x = a.x + adv.x; e.x = e.x > 0.f ? e.x : NEG_SLOPE * e.x; e.x = __expf(e.x);
            e.y = a.y + adv.y; e.y = e.y > 0.f ? e.y : NEG_SLOPE * e.y; e.y = __expf(e.y);
            e.z = a.z + adv.z; e.z = e.z > 0.f ? e.z : NEG_SLOPE * e.z; e.z = __expf(e.z);
            e.w = a.w + adv.w; e.w = e.w > 0.f ? e.w : NEG_SLOPE * e.w; e.w = __expf(e.w);
            s_w[wv][l] = e;
        }
        // phase 2: weighted gather; src/w via LDS broadcast, 8 gathers in flight
        int p = 0;
        for (; p + 8 <= cl; p += 8) {
            int ss[8]; float ww[8]; unsigned vv[8];
#pragma unroll
            for (int i = 0; i < 8; i++) {
                ss[i] = s_src[wv][p + i];
                ww[i] = ((const float*)&s_w[wv][p + i])[head];
            }
#pragma unroll
            for (int i = 0; i < 8; i++)
                vv[i] = *(const unsigned*)(h1b + (unsigned)ss[i] * 256u + lb4);
#pragma unroll
            for (int i = 0; i < 8; i++) {
                den += ww[i];
                if ((i & 3) == 0) fma_fp8x4(acc0, ww[i], vv[i]);
                if ((i & 3) == 1) fma_fp8x4(acc1, ww[i], vv[i]);
                if ((i & 3) == 2) fma_fp8x4(acc2, ww[i], vv[i]);
                if ((i & 3) == 3) fma_fp8x4(acc3, ww[i], vv[i]);
            }
        }
        for (; p + 4 <= cl; p += 4) {
            int sA = s_src[wv][p],     sB = s_src[wv][p + 1];
            int sC = s_src[wv][p + 2], sD = s_src[wv][p + 3];
            float wA = ((const float*)&s_w[wv][p    ])[head];
            float wB = ((const float*)&s_w[wv][p + 1])[head];
            float wC = ((const float*)&s_w[wv][p + 2])[head];
            float wD = ((const float*)&s_w[wv][p + 3])[head];
            unsigned vA = *(const unsigned*)(h1b + (unsigned)sA * 256u + lb4);
            unsigned vB = *(const unsigned*)(h1b + (unsigned)sB * 256u + lb4);
            unsigned vC = *(const unsigned*)(h1b + (unsigned)sC * 256u + lb4);
            unsigned vD = *(const unsigned*)(h1b + (unsigned)sD * 256u + lb4);
            den += (wA + wB) + (wC + wD);
            fma_fp8x4(acc0, wA, vA); fma_fp8x4(acc1, wB, vB);
            fma_fp8x4(acc2, wC, vC); fma_fp8x4(acc3, wD, vD);
        }
        for (; p < cl; p++) {
            int s = s_src[wv][p];
            float wg = ((const float*)&s_w[wv][p])[head];
            unsigned v = *(const unsigned*)(h1b + (unsigned)s * 256u + lb4);
            den += wg;
            fma_fp8x4(acc0, wg, v);
        }
    }
    float4 acc;
    acc.x = (acc0.x + acc1.x) + (acc2.x + acc3.x);
    acc.y = (acc0.y + acc1.y) + (acc2.y + acc3.y);
    acc.z = (acc0.z + acc1.z) + (acc2.z + acc3.z);
    acc.w = (acc0.w + acc1.w) + (acc2.w + acc3.w);
    float inv = 1.f / den;
    float4 b = ((const float4*)b1)[l];
    float r0 = acc.x * inv + b.x; r0 = r0 > 0.f ? r0 : 0.f;
    float r1 = acc.y * inv + b.y; r1 = r1 > 0.f ? r1 : 0.f;
    float r2 = acc.z * inv + b.z; r2 = r2 > 0.f ? r2 : 0.f;
    float r3 = acc.w * inv + b.w; r3 = r3 > 0.f ? r3 : 0.f;
    unsigned short u0 = __builtin_bit_cast(unsigned short, __float2half(r0));
    unsigned short u1 = __builtin_bit_cast(unsigned short, __float2half(r1));
    unsigned short u2 = __builtin_bit_cast(unsigned short, __float2half(r2));
    unsigned short u3 = __builtin_bit_cast(unsigned short, __float2half(r3));
    uint2 st;
    st.x = (unsigned)u0 | ((unsigned)u1 << 16);
    st.y = (unsigned)u2 | ((unsigned)u3 << 16);
    *(uint2*)((char*)hbh + (unsigned)n * 512u + (unsigned)l * 8u) = st;
}

// ---------------- GEMM2 via f16 MFMA: LDS-staged A and B tiles, fused att dots ----------------
__global__ __launch_bounds__(256) void k_gemm2_mfma(const _Float16* __restrict__ hbh,
                                                    const _Float16* __restrict__ w2t,
                                                    const float* __restrict__ att_s2,
                                                    const float* __restrict__ att_d2,
                                                    __half* __restrict__ h2h,
                                                    float* __restrict__ as2, float* __restrict__ ad2, int N) {
    __shared__ _Float16 Hs[64 * LDP];
    __shared__ _Float16 Ws[48 * LDP];
    int tid = threadIdx.x;
    int row0 = blockIdx.x * 64;
#pragma unroll
    for (int it = 0; it < 8; it++) {
        int c = tid + it * 256;       // 2048 chunks of 16B
        int r = c >> 5, q = c & 31;
        uint4 v = make_uint4(0, 0, 0, 0);
        if (row0 + r < N) v = ((const uint4*)hbh)[(size_t)(row0 + r) * 32 + q];
        *(uint4*)&Hs[r * LDP + q * 8] = v;
    }
#pragma unroll
    for (int it = 0; it < 6; it++) {
        int c = tid + it * 256;       // 1536 chunks
        int r = c >> 5, q = c & 31;
        uint4 v = ((const uint4*)w2t)[c];
        *(uint4*)&Ws[r * LDP + q * 8] = v;
    }
    __syncthreads();
    int w = tid >> 6, l = tid & 63;
    int hi = l >> 4, lo = l & 15;
    f32x4 acc[3] = {};
#pragma unroll
    for (int kk = 0; kk < 8; kk++) {
        half8v a = *(const half8v*)&Hs[(16 * w + lo) * LDP + kk * 32 + 8 * hi];
#pragma unroll
        for (int jb = 0; jb < 3; jb++) {
            half8v b = *(const half8v*)&Ws[(16 * jb + lo) * LDP + kk * 32 + 8 * hi];
            acc[jb] = __builtin_amdgcn_mfma_f32_16x16x32_f16(a, b, acc[jb], 0, 0, 0);
        }
    }
    float asr[3], adr[3];
#pragma unroll
    for (int jb = 0; jb < 3; jb++) {
        int c = 16 * jb + lo;
        asr[jb] = (c < 40) ? att_s2[c] : 0.f;
        adr[jb] = (c < 40) ? att_d2[c] : 0.f;
    }
#pragma unroll
    for (int j = 0; j < 4; j++) {
        int r = row0 + 16 * w + 4 * hi + j;
        float s = 0.f, d = 0.f;
#pragma unroll
        for (int jb = 0; jb < 3; jb++) {
            float v = acc[jb][j];
            s += v * asr[jb];
            d += v * adr[jb];
            int c = 16 * jb + lo;
            if (c < 40 && r < N) h2h[(size_t)r * 40 + c] = __float2half(v);
        }
        s += __shfl_xor(s, 1); s += __shfl_xor(s, 2); s += __shfl_xor(s, 4); s += __shfl_xor(s, 8);
        d += __shfl_xor(d, 1); d += __shfl_xor(d, 2); d += __shfl_xor(d, 4); d += __shfl_xor(d, 8);
        if (lo == 0 && r < N) { as2[r] = s; ad2[r] = d; }
    }
}

// ---------------- layer2 fused softmax-aggregation + bias + log_softmax: 2-phase ----------------
__global__ __launch_bounds__(256) void k_agg2(const __half* __restrict__ h2h, const float* __restrict__ as2,
                                              const float* __restrict__ ad2, const int* __restrict__ row_start,
                                              const int* __restrict__ csr_src, const float* __restrict__ b2,
                                              float* __restrict__ out, int N) {
    __shared__ int   s_src[4][64];
    __shared__ float s_w[4][64];
    int wv = threadIdx.x >> 6, l = threadIdx.x & 63;
    int n = blockIdx.x * 4 + wv;
    if (n >= N) return;
    int s0 = row_start[n], s1 = row_start[n + 1];
    int grp = l / 20, li = l - grp * 20;     // grp 3 = lanes 60..63 idle in phase 2
    unsigned li4 = (unsigned)li * 4u;
    const char* h2b = (const char*)h2h;
    float ad = ad2[n];
    float2 accA = make_float2(0.f, 0.f), accB = accA;
    float denA = 0.f, denB = 0.f;
    bool act = grp < 3;
    for (int c0 = s0; c0 < s1; c0 += 64) {
        int cl = min(64, s1 - c0);
        if (l < cl) {
            int si = csr_src[c0 + l];
            s_src[wv][l] = si;
            float e = as2[si] + ad;
            e = e > 0.f ? e : NEG_SLOPE * e;
            s_w[wv][l] = __expf(e);
        }
        if (act) {
            int p = grp;
            for (; p + 3 < cl; p += 6) {
                int sA = s_src[wv][p], sB = s_src[wv][p + 3];
                float wA = s_w[wv][p], wB = s_w[wv][p + 3];
                unsigned vA = *(const unsigned*)(h2b + (unsigned)sA * 80u + li4);
                unsigned vB = *(const unsigned*)(h2b + (unsigned)sB * 80u + li4);
                denA += wA; denB += wB;
                float2 fA = __half22float2(__builtin_bit_cast(__half2, vA));
                float2 fB = __half22float2(__builtin_bit_cast(__half2, vB));
                accA.x += wA * fA.x; accA.y += wA * fA.y;
                accB.x += wB * fB.x; accB.y += wB * fB.y;
            }
            for (; p < cl; p += 3) {
                int si = s_src[wv][p];
                float w = s_w[wv][p];
                unsigned v = *(const unsigned*)(h2b + (unsigned)si * 80u + li4);
                denA += w;
                float2 f = __half22float2(__builtin_bit_cast(__half2, v));
                accA.x += w * f.x; accA.y += w * f.y;
            }
        }
    }
    float den = denA + denB;
    float2 acc = make_float2(accA.x + accB.x, accA.y + accB.y);
    float den_t = __shfl(den, li) + __shfl(den, 20 + li) + __shfl(den, 40 + li);
    float ax = acc.x + __shfl(acc.x, l + 20) + __shfl(acc.x, l + 40);
    float ay = acc.y + __shfl(acc.y, l + 20) + __shfl(acc.y, l + 40);
    float inv = 1.f / den_t;
    float lg0 = -1e30f, lg1 = -1e30f;
    if (l < 20) {
        lg0 = ax * inv + b2[2 * l];
        lg1 = ay * inv + b2[2 * l + 1];
    }
    float mx = fmaxf(lg0, lg1);
    for (int off = 32; off; off >>= 1) mx = fmaxf(mx, __shfl_xor(mx, off));
    float s = (l < 20) ? (__expf(lg0 - mx) + __expf(lg1 - mx)) : 0.f;
    for (int off = 32; off; off >>= 1) s += __shfl_xor(s, off);
    float ls = logf(s);
    if (l < 20) {
        out[(size_t)n * 40 + 2 * l]     = lg0 - mx - ls;
        out[(size_t)n * 40 + 2 * l + 1] = lg1 - mx - ls;
    }
}

extern "C" void kernel_launch(void* const* d_in, const int* in_sizes, int n_in,
                              void* d_out, int out_size, void* d_ws, size_t ws_size,
                              hipStream_t stream) {
    const float* x      = (const float*)d_in[0];
    const int*   ei     = (const int*)d_in[1];
    const float* W1     = (const float*)d_in[2];
    const float* att_s1 = (const float*)d_in[3];
    const float* att_d1 = (const float*)d_in[4];
    const float* b1     = (const float*)d_in[5];
    const float* W2     = (const float*)d_in[6];
    const float* att_s2 = (const float*)d_in[7];
    const float* att_d2 = (const float*)d_in[8];
    const float* b2     = (const float*)d_in[9];

    int N = in_sizes[0] / 256;
    int E = in_sizes[1] / 2;
    int Et = E + N;

    char* ws = (char*)d_ws;
    size_t off = 0;
    auto alloc = [&](size_t bytes) -> void* {
        void* p = ws + off;
        off += (bytes + 255) / 256 * 256;
        return p;
    };
    unsigned char* h1f = (unsigned char*)alloc((size_t)N * 256);   // fp8 gather table
    __half* hbh = (__half*)alloc((size_t)N * 256 * 2);
    __half* h2h = (__half*)alloc((size_t)N * 40 * 2);
    unsigned short* w1t = (unsigned short*)alloc((size_t)256 * 256 * 2);
    __half* w2t = (__half*)alloc((size_t)48 * 256 * 2);
    float* as1 = (float*)alloc((size_t)N * 4 * 4);
    float* ad1 = (float*)alloc((size_t)N * 4 * 4);
    float* as2 = (float*)alloc((size_t)N * 4);
    float* ad2 = (float*)alloc((size_t)N * 4);
    int* deg       = (int*)alloc((size_t)N * 4);
    int* rank      = (int*)alloc((size_t)Et * 4);
    int* row_start = (int*)alloc((size_t)(N + 1) * 4);
    int* csr_src   = (int*)alloc((size_t)Et * 4);
    int NB = (N + 255) / 256;
    int* bsums = (int*)alloc((size_t)NB * 4);

    hipMemsetAsync(deg, 0, (size_t)N * 4, stream);

    int degB = (Et + 255) / 256;
    k_deg_cvt<<<degB + 304, 256, 0, stream>>>(ei, E, N, degB, deg, rank, W1, W2, w1t, w2t);
    k_scan_block<<<NB, 256, 0, stream>>>(deg, N, row_start, bsums);
    k_scan_add<<<NB, 256, 0, stream>>>(row_start, bsums, N, Et, NB);
    k_scatter<<<degB, 256, 0, stream>>>(ei, rank, E, N, row_start, csr_src);

    k_gemm1_mfma<<<(N + 63) / 64, 256, 0, stream>>>(x, w1t, att_s1, att_d1, h1f, as1, ad1, N);
    k_agg1<<<(N + 3) / 4, 256, 0, stream>>>(h1f, as1, ad1, row_start, csr_src, b1, hbh, N);
    k_gemm2_mfma<<<(N + 63) / 64, 256, 0, stream>>>((const _Float16*)hbh, (const _Float16*)w2t,
                                                    att_s2, att_d2, h2h, as2, ad2, N);
    k_agg2<<<(N + 3) / 4, 256, 0, stream>>>(h2h, as2, ad2, row_start, csr_src, b2, (float*)d_out, N);
}